// Round 11
// baseline (359.656 us; speedup 1.0000x reference)
//
#include <hip/hip_runtime.h>

#define N_NODES 50000
#define N_EDGES 800000
#define DIM 128
#define OUTD 47
#define NBK 196                          // dst buckets of 256 nodes
#define EPB 4096                         // edges per histogram/bin block
#define NBIN ((N_EDGES + EPB - 1) / EPB) // 196
#define XCVT_NB (N_NODES * DIM / 8 / 256) // 3125 blocks, 8 elems/thread
#define WCVT_NB (DIM + DIM + 48)         // 304 weight-row blocks

typedef __attribute__((ext_vector_type(8))) short v8s;
typedef __attribute__((ext_vector_type(8))) unsigned short v8u;
typedef __attribute__((ext_vector_type(4))) float v4f;
typedef __attribute__((ext_vector_type(2))) float v2f;

static __device__ __forceinline__ unsigned short f2bf(float f) {
    union { float f; unsigned int u; } v; v.f = f;
    unsigned int x = v.u;
    return (unsigned short)((x + 0x7fffu + ((x >> 16) & 1u)) >> 16); // RNE
}
static __device__ __forceinline__ unsigned char f2fp8(float f) {
    unsigned int pk = __builtin_amdgcn_cvt_pk_fp8_f32(f, f, 0, false);
    return (unsigned char)(pk & 0xffu);
}

// ---------------- prep: x->bf16+fp8 | per-block bucket hist partials | weight cvt ----------------
// One kernel, three block ranges. No global atomics anywhere (round-6 lesson: 473 us).
__global__ __launch_bounds__(256) void k_prep(const float* __restrict__ x,
                                              unsigned short* __restrict__ xb,
                                              unsigned int* __restrict__ x8,
                                              const int* __restrict__ dst,
                                              int* __restrict__ parts,
                                              const float* __restrict__ ws1, const float* __restrict__ wn1,
                                              const float* __restrict__ ws2, const float* __restrict__ wn2,
                                              const float* __restrict__ ws3, const float* __restrict__ wn3,
                                              unsigned short* __restrict__ wb1,
                                              unsigned short* __restrict__ wb2,
                                              unsigned short* __restrict__ wb3) {
    __shared__ int hist[NBK];
    const int bx = blockIdx.x, tid = threadIdx.x;
    if (bx < XCVT_NB) {
        int i = bx * 256 + tid; // 8 elems per thread
        float4 v0 = ((const float4*)x)[i * 2];
        float4 v1 = ((const float4*)x)[i * 2 + 1];
        ushort4 o0, o1;
        o0.x = f2bf(v0.x); o0.y = f2bf(v0.y); o0.z = f2bf(v0.z); o0.w = f2bf(v0.w);
        o1.x = f2bf(v1.x); o1.y = f2bf(v1.y); o1.z = f2bf(v1.z); o1.w = f2bf(v1.w);
        ((ushort4*)xb)[i * 2] = o0;
        ((ushort4*)xb)[i * 2 + 1] = o1;
        unsigned int a = __builtin_amdgcn_cvt_pk_fp8_f32(v0.x, v0.y, 0, false);
        a = __builtin_amdgcn_cvt_pk_fp8_f32(v0.z, v0.w, a, true);
        unsigned int b = __builtin_amdgcn_cvt_pk_fp8_f32(v1.x, v1.y, 0, false);
        b = __builtin_amdgcn_cvt_pk_fp8_f32(v1.z, v1.w, b, true);
        uint2 o; o.x = a; o.y = b;
        ((uint2*)x8)[i] = o;
    } else if (bx < XCVT_NB + NBIN) {
        const int j = bx - XCVT_NB;
        for (int i = tid; i < NBK; i += 256) hist[i] = 0;
        __syncthreads();
        const int e0 = j * EPB;
        const int ecnt = min(EPB, N_EDGES - e0);
        for (int r = tid; r < ecnt; r += 256)
            atomicAdd(&hist[dst[e0 + r] >> 8], 1); // LDS only
        __syncthreads();
        for (int i = tid; i < NBK; i += 256) parts[j * NBK + i] = hist[i];
    } else {
        int b2 = bx - XCVT_NB - NBIN; // weight row
        const float *sw, *nw; unsigned short* ob; int j, J;
        if (b2 < DIM)            { sw = ws1; nw = wn1; ob = wb1; j = b2;            J = DIM; }
        else if (b2 < 2 * DIM)   { sw = ws2; nw = wn2; ob = wb2; j = b2 - DIM;      J = DIM; }
        else                     { sw = ws3; nw = wn3; ob = wb3; j = b2 - 2 * DIM;  J = OUTD; }
        int k = tid;
        float v = 0.f;
        if (j < J) v = (k < DIM) ? sw[j * DIM + k] : nw[j * DIM + (k - DIM)];
        ob[j * 256 + k] = f2bf(v);
    }
}

// ---------------- scan2: bucket totals, boffB, exact per-(block,bucket) bases ----------------
__global__ __launch_bounds__(256) void k_scan2(const int* __restrict__ parts,
                                               int* __restrict__ gbase,
                                               int* __restrict__ boffB,
                                               int* __restrict__ btot,
                                               int* __restrict__ row_ptr) {
    __shared__ int s[256];
    const int t = threadIdx.x;
    int tot = 0;
    if (t < NBK)
        for (int i = 0; i < NBIN; ++i) tot += parts[i * NBK + t];
    s[t] = tot;
    __syncthreads();
    for (int off = 1; off < 256; off <<= 1) {
        int u = (t >= off) ? s[t - off] : 0;
        __syncthreads();
        s[t] += u;
        __syncthreads();
    }
    if (t < NBK) {
        int run = s[t] - tot; // exclusive bucket base
        boffB[t] = run; btot[t] = tot;
        for (int i = 0; i < NBIN; ++i) {
            gbase[i * NBK + t] = run;
            run += parts[i * NBK + t];
        }
    }
    if (t == 255) row_ptr[N_NODES] = s[255]; // == N_EDGES
}

// ---------------- bin: place edges at precomputed bases (LDS atomics only) ----------------
__global__ __launch_bounds__(256) void k_bin(const int* __restrict__ src,
                                             const int* __restrict__ dst,
                                             const int* __restrict__ gbase,
                                             unsigned int* __restrict__ packed) {
    __shared__ int gb[NBK], cnt[NBK];
    const int t = threadIdx.x;
    for (int i = t; i < NBK; i += 256) { gb[i] = gbase[blockIdx.x * NBK + i]; cnt[i] = 0; }
    __syncthreads();
    const int e0 = blockIdx.x * EPB;
    const int ecnt = min(EPB, N_EDGES - e0);
    for (int r = t; r < ecnt; r += 256) {
        int s = src[e0 + r], d = dst[e0 + r];
        int b = d >> 8;
        int loc = atomicAdd(&cnt[b], 1); // LDS
        packed[gb[b] + loc] = ((unsigned int)s << 8) | (unsigned int)(d & 255);
    }
}

// ---------------- place: local hist -> row_ptr for own 256 nodes, scatter src_sorted ----------------
__global__ __launch_bounds__(256) void k_place(const unsigned int* __restrict__ packed,
                                               const int* __restrict__ boffB,
                                               const int* __restrict__ btot,
                                               int* __restrict__ row_ptr,
                                               int* __restrict__ src_sorted) {
    __shared__ int hist[256], cur[256], s[256];
    const int b = blockIdx.x, t = threadIdx.x;
    hist[t] = 0;
    __syncthreads();
    const int base = boffB[b], cb = btot[b];
    for (int i = t; i < cb; i += 256)
        atomicAdd(&hist[packed[base + i] & 255u], 1); // LDS, ~16 avg per counter
    __syncthreads();
    int v = hist[t];
    s[t] = v;
    __syncthreads();
    for (int off = 1; off < 256; off <<= 1) {
        int u = (t >= off) ? s[t - off] : 0;
        __syncthreads();
        s[t] += u;
        __syncthreads();
    }
    int excl = base + s[t] - v;
    int node = b * 256 + t;
    if (node < N_NODES) row_ptr[node] = excl;
    cur[t] = excl;
    __syncthreads();
    for (int i = t; i < cb; i += 256) {
        unsigned int pkt = packed[base + i];
        int pos = atomicAdd(&cur[pkt & 255u], 1);
        src_sorted[pos] = (int)(pkt >> 8); // lands in this bucket's ~16KB region
    }
}

// ---------------- fused layer: mean-agg (fp8 gather -> LDS) + LDS MFMA GEMM + epilogue ----------------
// Block = 64 nodes, 256 threads. Alds holds concat [self(128) | mean(128)] bf16, XOR-swizzled
// so ds_read_b128 is conflict-free. Means computed in-block (16-lane group per node, fp32 acc,
// bf16 pack -- numerically identical to the old meanb path). W processed in NH halves of JH rows
// (64KB LDS cap), restaged between halves. Epilogue writes bf16 h + fp8 h (next layer's gather).
template <int JH, int NH, int TPW, bool RELU, bool OUTBF>
__global__ __launch_bounds__(256) void k_layer(const unsigned short* __restrict__ selfb,
                                               const unsigned char* __restrict__ h8in,
                                               const unsigned short* __restrict__ Wb,
                                               const float* __restrict__ bias,
                                               const int* __restrict__ row_ptr,
                                               const int* __restrict__ srcs,
                                               void* __restrict__ out,
                                               unsigned char* __restrict__ out8,
                                               int outdim) {
    __shared__ unsigned short Alds[64 * 256];   // 32 KB
    __shared__ unsigned short Wlds[JH * 256];   // 32 KB (JH=64) / 24 KB (JH=48)
    const int tid = threadIdx.x;
    const int m0 = blockIdx.x * 64;
    // ---- stage self half (cols 0..127) ----
    #pragma unroll
    for (int i = 0; i < 4; ++i) {
        int t = tid + 256 * i;
        int row = t >> 4, ch = t & 15;
        int node = m0 + row; if (node >= N_NODES) node = N_NODES - 1;
        v8u v = *(const v8u*)(selfb + (size_t)node * DIM + ch * 8);
        *(v8u*)(Alds + row * 256 + ((ch * 8) ^ ((row & 7) * 8))) = v;
    }
    // ---- compute means into cols 128..255 (16-lane group per node, 4 nodes per group) ----
    {
        const int g = tid & 15, sl = tid >> 4;
        for (int k = 0; k < 4; ++k) {
            int row = sl * 4 + k;
            int n = m0 + row;
            float a0=0.f,a1=0.f,a2=0.f,a3=0.f,a4=0.f,a5=0.f,a6=0.f,a7=0.f;
            int d = 0;
            if (n < N_NODES) {
                int start = row_ptr[n], end = row_ptr[n + 1];
                d = end - start;
                int e = start;
                for (; e + 2 <= end; e += 2) {
                    int s0 = srcs[e], s1 = srcs[e + 1];
                    uint2 u0 = *(const uint2*)(h8in + (size_t)s0 * DIM + g * 8);
                    uint2 u1 = *(const uint2*)(h8in + (size_t)s1 * DIM + g * 8);
                    v2f p0 = __builtin_amdgcn_cvt_pk_f32_fp8(u0.x, false);
                    v2f p1 = __builtin_amdgcn_cvt_pk_f32_fp8(u0.x, true);
                    v2f p2 = __builtin_amdgcn_cvt_pk_f32_fp8(u0.y, false);
                    v2f p3 = __builtin_amdgcn_cvt_pk_f32_fp8(u0.y, true);
                    v2f q0 = __builtin_amdgcn_cvt_pk_f32_fp8(u1.x, false);
                    v2f q1 = __builtin_amdgcn_cvt_pk_f32_fp8(u1.x, true);
                    v2f q2 = __builtin_amdgcn_cvt_pk_f32_fp8(u1.y, false);
                    v2f q3 = __builtin_amdgcn_cvt_pk_f32_fp8(u1.y, true);
                    a0 += p0[0] + q0[0]; a1 += p0[1] + q0[1];
                    a2 += p1[0] + q1[0]; a3 += p1[1] + q1[1];
                    a4 += p2[0] + q2[0]; a5 += p2[1] + q2[1];
                    a6 += p3[0] + q3[0]; a7 += p3[1] + q3[1];
                }
                if (e < end) {
                    int s0 = srcs[e];
                    uint2 u0 = *(const uint2*)(h8in + (size_t)s0 * DIM + g * 8);
                    v2f p0 = __builtin_amdgcn_cvt_pk_f32_fp8(u0.x, false);
                    v2f p1 = __builtin_amdgcn_cvt_pk_f32_fp8(u0.x, true);
                    v2f p2 = __builtin_amdgcn_cvt_pk_f32_fp8(u0.y, false);
                    v2f p3 = __builtin_amdgcn_cvt_pk_f32_fp8(u0.y, true);
                    a0 += p0[0]; a1 += p0[1]; a2 += p1[0]; a3 += p1[1];
                    a4 += p2[0]; a5 += p2[1]; a6 += p3[0]; a7 += p3[1];
                }
            }
            float inv = (d > 0) ? 1.f / (float)d : 0.f;
            v8u o;
            o[0]=f2bf(a0*inv); o[1]=f2bf(a1*inv); o[2]=f2bf(a2*inv); o[3]=f2bf(a3*inv);
            o[4]=f2bf(a4*inv); o[5]=f2bf(a5*inv); o[6]=f2bf(a6*inv); o[7]=f2bf(a7*inv);
            *(v8u*)(Alds + row * 256 + ((128 + g * 8) ^ ((row & 7) * 8))) = o;
        }
    }
    // ---- stage W half 0 ----
    #pragma unroll
    for (int i = 0; i < JH / 8; ++i) {
        int t = tid + 256 * i;
        int row = t >> 5, ch = t & 31;
        v8u v = *(const v8u*)(Wb + (size_t)row * 256 + ch * 8);
        *(v8u*)(Wlds + row * 256 + ((ch * 8) ^ ((row & 7) * 8))) = v;
    }
    __syncthreads();
    const int lane = tid & 63, wv = tid >> 6;
    const int m = lane & 15, qd = lane >> 4;
    const int arow = wv * 16 + m;
    #pragma unroll 1
    for (int h = 0; h < NH; ++h) {
        if (h > 0) {
            __syncthreads(); // all waves done reading Wlds (half h-1)
            #pragma unroll
            for (int i = 0; i < JH / 8; ++i) {
                int t = tid + 256 * i;
                int row = t >> 5, ch = t & 31;
                v8u v = *(const v8u*)(Wb + (size_t)(h * JH + row) * 256 + ch * 8);
                *(v8u*)(Wlds + row * 256 + ((ch * 8) ^ ((row & 7) * 8))) = v;
            }
            __syncthreads();
        }
        v4f acc[TPW] = {};
        #pragma unroll
        for (int c = 0; c < 8; ++c) {
            const int koff = c * 32 + qd * 8;
            v8s af = *(const v8s*)(Alds + arow * 256 + (koff ^ ((arow & 7) * 8)));
            #pragma unroll
            for (int t = 0; t < TPW; ++t) {
                int wrow = t * 16 + m;
                v8s wf = *(const v8s*)(Wlds + wrow * 256 + (koff ^ ((wrow & 7) * 8)));
                acc[t] = __builtin_amdgcn_mfma_f32_16x16x32_bf16(af, wf, acc[t], 0, 0, 0);
            }
        }
        #pragma unroll
        for (int t = 0; t < TPW; ++t) {
            int col = h * JH + t * 16 + m;
            bool colok = (col < outdim);
            float bv = colok ? bias[col] : 0.f;
            #pragma unroll
            for (int r = 0; r < 4; ++r) {
                int nrow = m0 + wv * 16 + qd * 4 + r;
                if (colok && nrow < N_NODES) {
                    float v = acc[t][r] + bv;
                    if (RELU) v = fmaxf(v, 0.f);
                    size_t idx = (size_t)nrow * outdim + col;
                    if (OUTBF) {
                        ((unsigned short*)out)[idx] = f2bf(v);
                        out8[idx] = f2fp8(v);
                    } else {
                        ((float*)out)[idx] = v;
                    }
                }
            }
        }
    }
}

extern "C" void kernel_launch(void* const* d_in, const int* in_sizes, int n_in,
                              void* d_out, int out_size, void* d_ws, size_t ws_size,
                              hipStream_t stream) {
    const float* x   = (const float*)d_in[0];
    const int*   src = (const int*)d_in[1];
    const int*   dst = (const int*)d_in[2];
    const float* ws1 = (const float*)d_in[3];
    const float* wn1 = (const float*)d_in[4];
    const float* b1  = (const float*)d_in[5];
    const float* ws2 = (const float*)d_in[6];
    const float* wn2 = (const float*)d_in[7];
    const float* b2  = (const float*)d_in[8];
    const float* ws3 = (const float*)d_in[9];
    const float* wn3 = (const float*)d_in[10];
    const float* b3  = (const float*)d_in[11];

    char* p = (char*)d_ws;
    auto alloc = [&](size_t bytes) { char* r = p; p += (bytes + 255) & ~(size_t)255; return r; };
    int*   row_ptr = (int*)alloc((size_t)(N_NODES + 1) * 4);
    int*   srcs    = (int*)alloc((size_t)N_EDGES * 4);
    unsigned int* packed = (unsigned int*)alloc((size_t)N_EDGES * 4);
    int*   parts   = (int*)alloc((size_t)NBIN * NBK * 4);
    int*   gbase   = (int*)alloc((size_t)NBIN * NBK * 4);
    int*   boffB   = (int*)alloc((size_t)NBK * 4);
    int*   btot    = (int*)alloc((size_t)NBK * 4);
    unsigned short* xb  = (unsigned short*)alloc((size_t)N_NODES * DIM * 2);
    unsigned short* h1b = (unsigned short*)alloc((size_t)N_NODES * DIM * 2);
    unsigned short* h2b = (unsigned short*)alloc((size_t)N_NODES * DIM * 2);
    unsigned char*  h8a = (unsigned char*)alloc((size_t)N_NODES * DIM);
    unsigned char*  h8b = (unsigned char*)alloc((size_t)N_NODES * DIM);
    unsigned short* wb1 = (unsigned short*)alloc((size_t)DIM * 256 * 2);
    unsigned short* wb2 = (unsigned short*)alloc((size_t)DIM * 256 * 2);
    unsigned short* wb3 = (unsigned short*)alloc((size_t)48 * 256 * 2);

    // 1: conversions + bucket hist partials (no global atomics, no memsets)
    k_prep<<<XCVT_NB + NBIN + WCVT_NB, 256, 0, stream>>>(
        x, xb, (unsigned int*)h8a, dst, parts,
        ws1, wn1, ws2, wn2, ws3, wn3, wb1, wb2, wb3);
    // 2-4: CSR
    k_scan2<<<1, 256, 0, stream>>>(parts, gbase, boffB, btot, row_ptr);
    k_bin<<<NBIN, 256, 0, stream>>>(src, dst, gbase, packed);
    k_place<<<NBK, 256, 0, stream>>>(packed, boffB, btot, row_ptr, srcs);

    const int MB = (N_NODES + 63) / 64; // 782

    // 5-7: fused layers (fp8 gather buffers ping-pong: a -> b -> a)
    k_layer<64, 2, 4, true, true><<<MB, 256, 0, stream>>>(
        xb, h8a, wb1, b1, row_ptr, srcs, h1b, h8b, DIM);
    k_layer<64, 2, 4, true, true><<<MB, 256, 0, stream>>>(
        h1b, h8b, wb2, b2, row_ptr, srcs, h2b, h8a, DIM);
    k_layer<48, 1, 3, false, false><<<MB, 256, 0, stream>>>(
        h2b, h8a, wb3, b3, row_ptr, srcs, d_out, nullptr, OUTD);
}

// Round 12
// 260.598 us; speedup vs baseline: 1.3801x; 1.3801x over previous
//
#include <hip/hip_runtime.h>

#define N_NODES 50000
#define N_EDGES 800000
#define DIM 128
#define OUTD 47
#define NBK 196                          // dst buckets of 256 nodes
#define EPB 4096                         // edges per histogram/bin block
#define NBIN ((N_EDGES + EPB - 1) / EPB) // 196
#define XCVT_NB (N_NODES * DIM / 8 / 256) // 3125 blocks, 8 elems/thread
#define WCVT_NB (DIM + DIM + 48)         // 304 weight-row blocks

typedef __attribute__((ext_vector_type(8))) short v8s;
typedef __attribute__((ext_vector_type(8))) unsigned short v8u;
typedef __attribute__((ext_vector_type(4))) float v4f;
typedef __attribute__((ext_vector_type(2))) float v2f;

static __device__ __forceinline__ unsigned short f2bf(float f) {
    union { float f; unsigned int u; } v; v.f = f;
    unsigned int x = v.u;
    return (unsigned short)((x + 0x7fffu + ((x >> 16) & 1u)) >> 16); // RNE
}
static __device__ __forceinline__ unsigned char f2fp8(float f) {
    unsigned int pk = __builtin_amdgcn_cvt_pk_fp8_f32(f, f, 0, false);
    return (unsigned char)(pk & 0xffu);
}

// ---------------- prep: x->bf16+fp8 | per-block bucket hist partials | weight cvt ----------------
// One kernel, three block ranges. No global atomics anywhere (round-6 lesson: 473 us).
__global__ __launch_bounds__(256) void k_prep(const float* __restrict__ x,
                                              unsigned short* __restrict__ xb,
                                              unsigned int* __restrict__ x8,
                                              const int* __restrict__ dst,
                                              int* __restrict__ parts,
                                              const float* __restrict__ ws1, const float* __restrict__ wn1,
                                              const float* __restrict__ ws2, const float* __restrict__ wn2,
                                              const float* __restrict__ ws3, const float* __restrict__ wn3,
                                              unsigned short* __restrict__ wb1,
                                              unsigned short* __restrict__ wb2,
                                              unsigned short* __restrict__ wb3) {
    __shared__ int hist[NBK];
    const int bx = blockIdx.x, tid = threadIdx.x;
    if (bx < XCVT_NB) {
        int i = bx * 256 + tid; // 8 elems per thread
        float4 v0 = ((const float4*)x)[i * 2];
        float4 v1 = ((const float4*)x)[i * 2 + 1];
        ushort4 o0, o1;
        o0.x = f2bf(v0.x); o0.y = f2bf(v0.y); o0.z = f2bf(v0.z); o0.w = f2bf(v0.w);
        o1.x = f2bf(v1.x); o1.y = f2bf(v1.y); o1.z = f2bf(v1.z); o1.w = f2bf(v1.w);
        ((ushort4*)xb)[i * 2] = o0;
        ((ushort4*)xb)[i * 2 + 1] = o1;
        unsigned int a = __builtin_amdgcn_cvt_pk_fp8_f32(v0.x, v0.y, 0, false);
        a = __builtin_amdgcn_cvt_pk_fp8_f32(v0.z, v0.w, a, true);
        unsigned int b = __builtin_amdgcn_cvt_pk_fp8_f32(v1.x, v1.y, 0, false);
        b = __builtin_amdgcn_cvt_pk_fp8_f32(v1.z, v1.w, b, true);
        uint2 o; o.x = a; o.y = b;
        ((uint2*)x8)[i] = o;
    } else if (bx < XCVT_NB + NBIN) {
        const int j = bx - XCVT_NB;
        for (int i = tid; i < NBK; i += 256) hist[i] = 0;
        __syncthreads();
        const int e0 = j * EPB;
        const int ecnt = min(EPB, N_EDGES - e0);
        for (int r = tid; r < ecnt; r += 256)
            atomicAdd(&hist[dst[e0 + r] >> 8], 1); // LDS only
        __syncthreads();
        for (int i = tid; i < NBK; i += 256) parts[j * NBK + i] = hist[i];
    } else {
        int b2 = bx - XCVT_NB - NBIN; // weight row
        const float *sw, *nw; unsigned short* ob; int j, J;
        if (b2 < DIM)            { sw = ws1; nw = wn1; ob = wb1; j = b2;            J = DIM; }
        else if (b2 < 2 * DIM)   { sw = ws2; nw = wn2; ob = wb2; j = b2 - DIM;      J = DIM; }
        else                     { sw = ws3; nw = wn3; ob = wb3; j = b2 - 2 * DIM;  J = OUTD; }
        int k = tid;
        float v = 0.f;
        if (j < J) v = (k < DIM) ? sw[j * DIM + k] : nw[j * DIM + (k - DIM)];
        ob[j * 256 + k] = f2bf(v);
    }
}

// ---------------- bin: local column-prefix of parts -> bases; place edges (LDS atomics only) ----------------
// Replaces the single-block k_scan2: each block recomputes the bucket prefix from parts
// (196 coalesced 784B rows, L2-resident) -- parallel instead of serial, one fewer dispatch.
__global__ __launch_bounds__(256) void k_bin(const int* __restrict__ src,
                                             const int* __restrict__ dst,
                                             const int* __restrict__ parts,
                                             unsigned int* __restrict__ packed) {
    __shared__ int s[256], gb[NBK], cnt[NBK];
    const int t = threadIdx.x;
    const int j = blockIdx.x;
    int ct = 0, cp = 0;
    for (int i = 0; i < NBIN; ++i) {
        int v = (t < NBK) ? parts[i * NBK + t] : 0;
        if (i == j) cp = ct;
        ct += v;
    }
    s[t] = ct;
    __syncthreads();
    for (int off = 1; off < 256; off <<= 1) {
        int u = (t >= off) ? s[t - off] : 0;
        __syncthreads();
        s[t] += u;
        __syncthreads();
    }
    if (t < NBK) { gb[t] = (s[t] - ct) + cp; cnt[t] = 0; } // bucket base + own-block offset
    __syncthreads();
    const int e0 = j * EPB;
    const int ecnt = min(EPB, N_EDGES - e0);
    for (int r = t; r < ecnt; r += 256) {
        int sv = src[e0 + r], d = dst[e0 + r];
        int b = d >> 8;
        int loc = atomicAdd(&cnt[b], 1); // LDS
        packed[gb[b] + loc] = ((unsigned int)sv << 8) | (unsigned int)(d & 255);
    }
}

// ---------------- place: local bucket scan + per-node hist -> row_ptr, scatter src_sorted ----------------
__global__ __launch_bounds__(256) void k_place(const unsigned int* __restrict__ packed,
                                               const int* __restrict__ parts,
                                               int* __restrict__ row_ptr,
                                               int* __restrict__ src_sorted) {
    __shared__ int s[256], baseL[NBK], totL[NBK];
    __shared__ int hist[256], cur[256];
    const int b = blockIdx.x, t = threadIdx.x;
    int ct = 0;
    for (int i = 0; i < NBIN; ++i)
        ct += (t < NBK) ? parts[i * NBK + t] : 0;
    s[t] = ct;
    hist[t] = 0;
    __syncthreads();
    for (int off = 1; off < 256; off <<= 1) {
        int u = (t >= off) ? s[t - off] : 0;
        __syncthreads();
        s[t] += u;
        __syncthreads();
    }
    if (t < NBK) { baseL[t] = s[t] - ct; totL[t] = ct; }
    __syncthreads();
    const int base = baseL[b], cb = totL[b];
    for (int i = t; i < cb; i += 256)
        atomicAdd(&hist[packed[base + i] & 255u], 1); // LDS, ~16 avg per counter
    __syncthreads();
    int v = hist[t];
    s[t] = v;
    __syncthreads();
    for (int off = 1; off < 256; off <<= 1) {
        int u = (t >= off) ? s[t - off] : 0;
        __syncthreads();
        s[t] += u;
        __syncthreads();
    }
    int excl = base + s[t] - v;
    int node = b * 256 + t;
    if (node < N_NODES) row_ptr[node] = excl;
    if (b == NBK - 1 && t == 255) row_ptr[N_NODES] = base + cb; // == N_EDGES
    cur[t] = excl;
    __syncthreads();
    for (int i = t; i < cb; i += 256) {
        unsigned int pkt = packed[base + i];
        int pos = atomicAdd(&cur[pkt & 255u], 1);
        src_sorted[pos] = (int)(pkt >> 8); // lands in this bucket's ~16KB region
    }
}

// ---------------- mean aggregation: 4 nodes/wave, 16 lanes/node, 4-edge unroll ----------------
// No LDS -> full occupancy (R11 lesson: the gather is latency-bound, lives on wave count).
__global__ __launch_bounds__(256) void k_agg8(const unsigned char* __restrict__ h8,
                                              const int* __restrict__ row_ptr,
                                              const int* __restrict__ srcs,
                                              unsigned short* __restrict__ meanb) {
    const int tid = threadIdx.x;
    const int lane = tid & 63, wv = tid >> 6;
    const int g = lane & 15, ns = lane >> 4;
    const int n = blockIdx.x * 16 + wv * 4 + ns;
    const int start = row_ptr[n], end = row_ptr[n + 1]; // uniform per 16-lane group
    float a0=0.f,a1=0.f,a2=0.f,a3=0.f,a4=0.f,a5=0.f,a6=0.f,a7=0.f;
    int e = start;
    for (; e + 4 <= end; e += 4) {
        int s0 = srcs[e], s1 = srcs[e + 1], s2 = srcs[e + 2], s3 = srcs[e + 3];
        uint2 u0 = *(const uint2*)(h8 + (size_t)s0 * DIM + g * 8);
        uint2 u1 = *(const uint2*)(h8 + (size_t)s1 * DIM + g * 8);
        uint2 u2 = *(const uint2*)(h8 + (size_t)s2 * DIM + g * 8);
        uint2 u3 = *(const uint2*)(h8 + (size_t)s3 * DIM + g * 8);
        v2f p0 = __builtin_amdgcn_cvt_pk_f32_fp8(u0.x, false);
        v2f p1 = __builtin_amdgcn_cvt_pk_f32_fp8(u0.x, true);
        v2f p2 = __builtin_amdgcn_cvt_pk_f32_fp8(u0.y, false);
        v2f p3 = __builtin_amdgcn_cvt_pk_f32_fp8(u0.y, true);
        v2f q0 = __builtin_amdgcn_cvt_pk_f32_fp8(u1.x, false);
        v2f q1 = __builtin_amdgcn_cvt_pk_f32_fp8(u1.x, true);
        v2f q2 = __builtin_amdgcn_cvt_pk_f32_fp8(u1.y, false);
        v2f q3 = __builtin_amdgcn_cvt_pk_f32_fp8(u1.y, true);
        v2f r0 = __builtin_amdgcn_cvt_pk_f32_fp8(u2.x, false);
        v2f r1 = __builtin_amdgcn_cvt_pk_f32_fp8(u2.x, true);
        v2f r2 = __builtin_amdgcn_cvt_pk_f32_fp8(u2.y, false);
        v2f r3 = __builtin_amdgcn_cvt_pk_f32_fp8(u2.y, true);
        v2f w0 = __builtin_amdgcn_cvt_pk_f32_fp8(u3.x, false);
        v2f w1 = __builtin_amdgcn_cvt_pk_f32_fp8(u3.x, true);
        v2f w2 = __builtin_amdgcn_cvt_pk_f32_fp8(u3.y, false);
        v2f w3 = __builtin_amdgcn_cvt_pk_f32_fp8(u3.y, true);
        a0 += (p0[0] + q0[0]) + (r0[0] + w0[0]);
        a1 += (p0[1] + q0[1]) + (r0[1] + w0[1]);
        a2 += (p1[0] + q1[0]) + (r1[0] + w1[0]);
        a3 += (p1[1] + q1[1]) + (r1[1] + w1[1]);
        a4 += (p2[0] + q2[0]) + (r2[0] + w2[0]);
        a5 += (p2[1] + q2[1]) + (r2[1] + w2[1]);
        a6 += (p3[0] + q3[0]) + (r3[0] + w3[0]);
        a7 += (p3[1] + q3[1]) + (r3[1] + w3[1]);
    }
    for (; e < end; ++e) {
        int s0 = srcs[e];
        uint2 u0 = *(const uint2*)(h8 + (size_t)s0 * DIM + g * 8);
        v2f p0 = __builtin_amdgcn_cvt_pk_f32_fp8(u0.x, false);
        v2f p1 = __builtin_amdgcn_cvt_pk_f32_fp8(u0.x, true);
        v2f p2 = __builtin_amdgcn_cvt_pk_f32_fp8(u0.y, false);
        v2f p3 = __builtin_amdgcn_cvt_pk_f32_fp8(u0.y, true);
        a0 += p0[0]; a1 += p0[1]; a2 += p1[0]; a3 += p1[1];
        a4 += p2[0]; a5 += p2[1]; a6 += p3[0]; a7 += p3[1];
    }
    int d = end - start;
    float inv = (d > 0) ? 1.f / (float)d : 0.f;
    v8u o;
    o[0]=f2bf(a0*inv); o[1]=f2bf(a1*inv); o[2]=f2bf(a2*inv); o[3]=f2bf(a3*inv);
    o[4]=f2bf(a4*inv); o[5]=f2bf(a5*inv); o[6]=f2bf(a6*inv); o[7]=f2bf(a7*inv);
    *(v8u*)(meanb + (size_t)n * DIM + g * 8) = o;
}

// ---------------- LDS-staged MFMA GEMM (whole K resident, XOR-swizzled) ----------------
template <int JT, int TPW, bool RELU, bool OUTBF>
__global__ __launch_bounds__(256) void k_gemm_lds(const unsigned short* __restrict__ Ab,
                                                  const unsigned short* __restrict__ Mb,
                                                  const unsigned short* __restrict__ Wb,
                                                  const float* __restrict__ bias,
                                                  void* __restrict__ out,
                                                  unsigned char* __restrict__ out8,
                                                  int outdim) {
    __shared__ unsigned short Alds[64 * 256];  // 32 KB
    __shared__ unsigned short Wlds[JT * 256];  // 32 KB (JT=64) / 24 KB (JT=48)
    const int tid = threadIdx.x;
    const int m0 = blockIdx.x * 64;
    const int j0 = blockIdx.y * JT;
    v8u ar[8];
    #pragma unroll
    for (int i = 0; i < 8; ++i) {
        int t = tid + 256 * i;
        int row = t >> 5, ch = t & 31;
        int node = m0 + row; if (node >= N_NODES) node = N_NODES - 1;
        const unsigned short* s = (ch < 16) ? (Ab + (size_t)node * DIM + ch * 8)
                                            : (Mb + (size_t)node * DIM + (ch - 16) * 8);
        ar[i] = *(const v8u*)s;
    }
    constexpr int WI = (JT * 32 + 255) / 256;
    v8u wr[WI];
    #pragma unroll
    for (int i = 0; i < WI; ++i) {
        int t = tid + 256 * i;
        if (t < JT * 32) {
            int row = t >> 5, ch = t & 31;
            wr[i] = *(const v8u*)(Wb + (size_t)(j0 + row) * 256 + ch * 8);
        }
    }
    #pragma unroll
    for (int i = 0; i < 8; ++i) {
        int t = tid + 256 * i;
        int row = t >> 5, ch = t & 31;
        *(v8u*)(Alds + row * 256 + ((ch * 8) ^ ((row & 7) * 8))) = ar[i];
    }
    #pragma unroll
    for (int i = 0; i < WI; ++i) {
        int t = tid + 256 * i;
        if (t < JT * 32) {
            int row = t >> 5, ch = t & 31;
            *(v8u*)(Wlds + row * 256 + ((ch * 8) ^ ((row & 7) * 8))) = wr[i];
        }
    }
    __syncthreads();
    const int lane = tid & 63, wv = tid >> 6;
    const int m = lane & 15, qd = lane >> 4;
    const int arow = wv * 16 + m;
    v4f acc[TPW] = {};
    #pragma unroll
    for (int c = 0; c < 8; ++c) {
        const int koff = c * 32 + qd * 8;
        v8s af = *(const v8s*)(Alds + arow * 256 + (koff ^ ((arow & 7) * 8)));
        #pragma unroll
        for (int t = 0; t < TPW; ++t) {
            int wrow = t * 16 + m;
            v8s wf = *(const v8s*)(Wlds + wrow * 256 + (koff ^ ((wrow & 7) * 8)));
            acc[t] = __builtin_amdgcn_mfma_f32_16x16x32_bf16(af, wf, acc[t], 0, 0, 0);
        }
    }
    #pragma unroll
    for (int t = 0; t < TPW; ++t) {
        int col = j0 + t * 16 + m;
        bool colok = (col < outdim);
        float bv = colok ? bias[col] : 0.f;
        #pragma unroll
        for (int r = 0; r < 4; ++r) {
            int nrow = m0 + wv * 16 + qd * 4 + r;
            if (colok && nrow < N_NODES) {
                float v = acc[t][r] + bv;
                if (RELU) v = fmaxf(v, 0.f);
                size_t idx = (size_t)nrow * outdim + col;
                if (OUTBF) {
                    ((unsigned short*)out)[idx] = f2bf(v);
                    out8[idx] = f2fp8(v);
                } else {
                    ((float*)out)[idx] = v;
                }
            }
        }
    }
}

extern "C" void kernel_launch(void* const* d_in, const int* in_sizes, int n_in,
                              void* d_out, int out_size, void* d_ws, size_t ws_size,
                              hipStream_t stream) {
    const float* x   = (const float*)d_in[0];
    const int*   src = (const int*)d_in[1];
    const int*   dst = (const int*)d_in[2];
    const float* ws1 = (const float*)d_in[3];
    const float* wn1 = (const float*)d_in[4];
    const float* b1  = (const float*)d_in[5];
    const float* ws2 = (const float*)d_in[6];
    const float* wn2 = (const float*)d_in[7];
    const float* b2  = (const float*)d_in[8];
    const float* ws3 = (const float*)d_in[9];
    const float* wn3 = (const float*)d_in[10];
    const float* b3  = (const float*)d_in[11];

    char* p = (char*)d_ws;
    auto alloc = [&](size_t bytes) { char* r = p; p += (bytes + 255) & ~(size_t)255; return r; };
    int*   row_ptr = (int*)alloc((size_t)(N_NODES + 1) * 4);
    int*   srcs    = (int*)alloc((size_t)N_EDGES * 4);
    unsigned int* packed = (unsigned int*)alloc((size_t)N_EDGES * 4);
    int*   parts   = (int*)alloc((size_t)NBIN * NBK * 4);
    unsigned short* xb    = (unsigned short*)alloc((size_t)N_NODES * DIM * 2);
    unsigned short* meanb = (unsigned short*)alloc((size_t)N_NODES * DIM * 2);
    unsigned short* h1b   = (unsigned short*)alloc((size_t)N_NODES * DIM * 2);
    unsigned short* h2b   = (unsigned short*)alloc((size_t)N_NODES * DIM * 2);
    unsigned char*  h8    = (unsigned char*)alloc((size_t)N_NODES * DIM);
    unsigned short* wb1 = (unsigned short*)alloc((size_t)DIM * 256 * 2);
    unsigned short* wb2 = (unsigned short*)alloc((size_t)DIM * 256 * 2);
    unsigned short* wb3 = (unsigned short*)alloc((size_t)48 * 256 * 2);

    // 1: conversions + bucket hist partials (no global atomics, no memsets)
    k_prep<<<XCVT_NB + NBIN + WCVT_NB, 256, 0, stream>>>(
        x, xb, (unsigned int*)h8, dst, parts,
        ws1, wn1, ws2, wn2, ws3, wn3, wb1, wb2, wb3);
    // 2-3: CSR (bucket prefix recomputed locally in each kernel; no serial scan dispatch)
    k_bin<<<NBIN, 256, 0, stream>>>(src, dst, parts, packed);
    k_place<<<NBK, 256, 0, stream>>>(packed, parts, row_ptr, srcs);

    const int MB = (N_NODES + 63) / 64; // 782
    const int AB = N_NODES / 16;        // 3125

    // layer 1
    k_agg8<<<AB, 256, 0, stream>>>(h8, row_ptr, srcs, meanb);
    k_gemm_lds<64, 4, true, true><<<dim3(MB, 2), 256, 0, stream>>>(xb, meanb, wb1, b1, h1b, h8, DIM);
    // layer 2
    k_agg8<<<AB, 256, 0, stream>>>(h8, row_ptr, srcs, meanb);
    k_gemm_lds<64, 4, true, true><<<dim3(MB, 2), 256, 0, stream>>>(h1b, meanb, wb2, b2, h2b, h8, DIM);
    // layer 3
    k_agg8<<<AB, 256, 0, stream>>>(h8, row_ptr, srcs, meanb);
    k_gemm_lds<48, 3, false, false><<<dim3(MB, 1), 256, 0, stream>>>(h2b, meanb, wb3, b3, d_out, nullptr, OUTD);
}